// Round 5
// baseline (367.671 us; speedup 1.0000x reference)
//
#include <hip/hip_runtime.h>
#include <math.h>

#define NB 4
#define SEQ 4096
#define HID 2048
#define DH 256
#define DV 512
#define CHUNK 128
#define NCH 32                  // SEQ/CHUNK
#define MROWS (NB * SEQ)        // 16384
#define GAMMA 0.96875f
#define GAMMA_INV 1.0322580645161290f
// log2(0.96875)
#define LOG2_GAMMA (-0.045803689613124794f)
// log2(10000)
#define LOG2_10000 13.287712379549449f

typedef __attribute__((ext_vector_type(8))) short short8;
typedef __attribute__((ext_vector_type(4))) float floatx4;

// ---------------------------------------------------------------------------
// helpers
// ---------------------------------------------------------------------------
__device__ __forceinline__ unsigned short bf16_rne(float v) {
    unsigned int u = __float_as_uint(v);
    u += 0x7fff + ((u >> 16) & 1);
    return (unsigned short)(u >> 16);
}
__device__ __forceinline__ float b2f(unsigned short h) {
    return __uint_as_float((unsigned int)h << 16);
}

// async global->LDS, 16 bytes per lane. LDS dest = wave-uniform base + lane*16.
__device__ __forceinline__ void gld16(const void* g, void* l) {
    __builtin_amdgcn_global_load_lds(
        reinterpret_cast<const __attribute__((address_space(1))) unsigned int*>(
            reinterpret_cast<uintptr_t>(g)),
        reinterpret_cast<__attribute__((address_space(3))) unsigned int*>(
            reinterpret_cast<uintptr_t>(l)),
        16, 0, 0);
}

// ---------------------------------------------------------------------------
// Kernel 0a: X fp32 -> bf16 row-major [M][K].
// ---------------------------------------------------------------------------
__global__ __launch_bounds__(256) void xcvt_kernel(
    const float* __restrict__ X, unsigned short* __restrict__ Xb)
{
    const int i = blockIdx.x * 256 + threadIdx.x;   // one float4 per thread
    float4 x = ((const float4*)X)[i];
    ushort4 h;
    h.x = bf16_rne(x.x); h.y = bf16_rne(x.y);
    h.z = bf16_rne(x.z); h.w = bf16_rne(x.w);
    ((ushort4*)Xb)[i] = h;
}

// ---------------------------------------------------------------------------
// Kernel 0b: W_Q|W_K|W_V fp32 [K][Nregion] -> transposed packed bf16 Bt[n][k].
// ---------------------------------------------------------------------------
__global__ __launch_bounds__(256) void wcvt_kernel(
    const float* __restrict__ WQ, const float* __restrict__ WK,
    const float* __restrict__ WV, unsigned short* __restrict__ Bt)
{
    __shared__ unsigned short sh[64][65];
    const int bid = blockIdx.x;         // 32 k-tiles * 16 n-tiles
    const int kt = bid & 31;
    const int ntile = bid >> 5;
    const int k0 = kt * 64, n0 = ntile * 64;

    const float* W; int ld, nl0;
    if (n0 < 256)      { W = WQ; ld = DH; nl0 = n0; }
    else if (n0 < 512) { W = WK; ld = DH; nl0 = n0 - 256; }
    else               { W = WV; ld = DV; nl0 = n0 - 512; }

    const int t = threadIdx.x;
#pragma unroll
    for (int p = 0; p < 4; p++) {
        const int kl = (t >> 4) + p * 16;
        const int ng = (t & 15) * 4;
        float4 w = *(const float4*)&W[(size_t)(k0 + kl) * ld + nl0 + ng];
        sh[kl][ng + 0] = bf16_rne(w.x);
        sh[kl][ng + 1] = bf16_rne(w.y);
        sh[kl][ng + 2] = bf16_rne(w.z);
        sh[kl][ng + 3] = bf16_rne(w.w);
    }
    __syncthreads();
#pragma unroll
    for (int p = 0; p < 4; p++) {
        const int nl = (t >> 4) + p * 16;
        const int kg = (t & 15) * 4;
        ushort4 h;
        h.x = sh[kg + 0][nl]; h.y = sh[kg + 1][nl];
        h.z = sh[kg + 2][nl]; h.w = sh[kg + 3][nl];
        *(ushort4*)&Bt[(size_t)(n0 + nl) * HID + k0 + kg] = h;
    }
}

// ---------------------------------------------------------------------------
// Kernel 1: QKV projection, bf16 MFMA + xPos epilogue.
// M=16384, N=1024, K=2048.
// ROUND 3: 256x256 tile, 8-wave (2Mx4N), 4-phase deep pipeline (T3+T4+T5).
// Grid = 64x4 = 256 blocks = exactly 1/CU, zero tail. BK=64, 32 K-tiles.
// 2x64KB LDS buffers; all 8 gld16 for K-tile t+1 issued at iter top into
// buf^1 (idle all iter); raw s_barrier phases (no implicit vmcnt drain);
// ONE s_waitcnt vmcnt(0) per iter after ph4 MFMA (~4 phases of hiding).
// XOR slot-swizzle carried from round 2 (measured zero bank conflicts).
// acc[8][4] floatx4 =128 VGPR + frags 64 -> ~220 VGPR, 2 waves/SIMD.
// Outputs (bf16): Qb[m][256], Kb[m][256], Kt[dh][m], Vt[dv][m].
// ---------------------------------------------------------------------------
__global__ __launch_bounds__(512, 2) void qkv_mfma_kernel(
    const unsigned short* __restrict__ Xb, const unsigned short* __restrict__ Bt,
    unsigned short* __restrict__ Qb, unsigned short* __restrict__ Kb,
    unsigned short* __restrict__ Kt, unsigned short* __restrict__ Vt)
{
    __shared__ unsigned short lds[2 * 32768];   // [buf][A 256x64 | B 256x64]

    // XCD-aware map: same-XCD blocks share the same A-panel (mt), 4 n-tiles.
    const int bid = blockIdx.x;          // 256 blocks
    const int xcd = bid & 7;
    const int idx = bid >> 3;            // 0..31
    const int mt  = (xcd << 3) | (idx >> 2);   // 64 m-tiles
    const int nt  = idx & 3;             // 4 n-tiles
    const int m0 = mt * 256, n0 = nt * 256;

    const int t = threadIdx.x;
    const int w = t >> 6, lane = t & 63;   // 8 waves
    const int wr = w >> 2;               // 0..1: row half (128 rows)
    const int wc = w & 3;                // 0..3: col quarter (64 cols)

    floatx4 acc[8][4];
#pragma unroll
    for (int i = 0; i < 8; i++)
#pragma unroll
        for (int j = 0; j < 4; j++) acc[i][j] = (floatx4)0.0f;

    // staging addressing: per gld16, lane l -> row rl = l>>3, LDS slot l&7
    // holding global slot (l&7)^rl  (XOR swizzle, row&7 == rl).
    const int rl = lane >> 3;
    const int sg = (lane & 7) ^ rl;

    // fragment addressing: row r, slot_g = (s<<2)|g; LDS slot = slot_g ^ (r&7)
    const int fr = lane & 15, g = lane >> 4;
    const int x7 = fr & 7;
    const int soff0 = ((g ^ x7) << 3);          // s=0, in ushort units
    const int soff1 = (((4 | g) ^ x7) << 3);    // s=1

#define STAGE_HT(isB, h, dbuf, kt)                                            \
    {                                                                         \
        const unsigned short* gsrc =                                          \
            ((isB) ? Bt + (size_t)(n0 + (h) * 128 + w * 16 + rl) * HID        \
                   : Xb + (size_t)(m0 + (h) * 128 + w * 16 + rl) * HID)       \
            + (size_t)(kt) * 64 + sg * 8;                                     \
        unsigned short* ldst = &lds[(dbuf) * 32768 + ((isB) ? 16384 : 0)      \
                                    + ((h) * 128 + w * 16) * 64];             \
        gld16(gsrc, ldst);                                                    \
        gld16(gsrc + (size_t)8 * HID, ldst + 8 * 64);                         \
    }

#define READ_A(ih)                                                            \
    _Pragma("unroll")                                                         \
    for (int i2 = 0; i2 < 4; i2++) {                                          \
        const int row = wr * 128 + ((ih) * 4 + i2) * 16 + fr;                 \
        ah[i2][0] = *(const short8*)&lds[cb + row * 64 + soff0];              \
        ah[i2][1] = *(const short8*)&lds[cb + row * 64 + soff1];              \
    }

#define READ_B(jh)                                                            \
    _Pragma("unroll")                                                         \
    for (int j2 = 0; j2 < 2; j2++) {                                          \
        const int row = wc * 64 + ((jh) * 2 + j2) * 16 + fr;                  \
        bh[(jh) * 2 + j2][0] = *(const short8*)&lds[cb + 16384 + row * 64 + soff0]; \
        bh[(jh) * 2 + j2][1] = *(const short8*)&lds[cb + 16384 + row * 64 + soff1]; \
    }

#define MFMA16(ib, jb)                                                        \
    _Pragma("unroll")                                                         \
    for (int i2 = 0; i2 < 4; i2++)                                            \
        _Pragma("unroll")                                                     \
        for (int j2 = 0; j2 < 2; j2++) {                                      \
            acc[(ib) + i2][(jb) + j2] = __builtin_amdgcn_mfma_f32_16x16x32_bf16( \
                ah[i2][0], bh[(jb) + j2][0], acc[(ib) + i2][(jb) + j2], 0, 0, 0); \
            acc[(ib) + i2][(jb) + j2] = __builtin_amdgcn_mfma_f32_16x16x32_bf16( \
                ah[i2][1], bh[(jb) + j2][1], acc[(ib) + i2][(jb) + j2], 0, 0, 0); \
        }

    // prologue: stage K-tile 0 into buf0, drain, align.
    STAGE_HT(0, 0, 0, 0); STAGE_HT(0, 1, 0, 0);
    STAGE_HT(1, 0, 0, 0); STAGE_HT(1, 1, 0, 0);
    asm volatile("s_waitcnt vmcnt(0)" ::: "memory");
    __builtin_amdgcn_s_barrier();
    __builtin_amdgcn_sched_barrier(0);

    int cur = 0;
    for (int kt = 0; kt < 32; ++kt) {
        const int nxt = cur ^ 1;
        if (kt + 1 < 32) {                 // stage next K-tile into idle buffer
            STAGE_HT(0, 0, nxt, kt + 1); STAGE_HT(0, 1, nxt, kt + 1);
            STAGE_HT(1, 0, nxt, kt + 1); STAGE_HT(1, 1, nxt, kt + 1);
        }
        const int cb = cur * 32768;
        short8 ah[4][2], bh[4][2];

        // ---- phase 1: C-quadrant (i 0-3, j 0-1), K=64 ----
        READ_A(0); READ_B(0);
        __builtin_amdgcn_s_barrier();
        __builtin_amdgcn_sched_barrier(0);
        __builtin_amdgcn_s_setprio(1);
        MFMA16(0, 0);
        __builtin_amdgcn_s_setprio(0);
        __builtin_amdgcn_s_barrier();
        __builtin_amdgcn_sched_barrier(0);

        // ---- phase 2: (i 0-3, j 2-3) ----
        READ_B(1);
        __builtin_amdgcn_s_barrier();
        __builtin_amdgcn_sched_barrier(0);
        __builtin_amdgcn_s_setprio(1);
        MFMA16(0, 2);
        __builtin_amdgcn_s_setprio(0);
        __builtin_amdgcn_s_barrier();
        __builtin_amdgcn_sched_barrier(0);

        // ---- phase 3: (i 4-7, j 0-1) ----
        READ_A(1);
        __builtin_amdgcn_s_barrier();
        __builtin_amdgcn_sched_barrier(0);
        __builtin_amdgcn_s_setprio(1);
        MFMA16(4, 0);
        __builtin_amdgcn_s_setprio(0);
        __builtin_amdgcn_s_barrier();
        __builtin_amdgcn_sched_barrier(0);

        // ---- phase 4: (i 4-7, j 2-3), then iter-end drain+align ----
        __builtin_amdgcn_s_setprio(1);
        MFMA16(4, 2);
        __builtin_amdgcn_s_setprio(0);
        asm volatile("s_waitcnt vmcnt(0)" ::: "memory");   // next-tile loads landed
        __builtin_amdgcn_s_barrier();
        __builtin_amdgcn_sched_barrier(0);
        cur = nxt;
    }
#undef STAGE_HT
#undef READ_A
#undef READ_B
#undef MFMA16

    // epilogue. C/D layout: col = lane&15, row = (lane>>4)*4 + reg.
    const int cl = lane & 15, rq = (lane >> 4) << 2;
    if (n0 >= 512) {
#pragma unroll
        for (int i = 0; i < 8; i++)
#pragma unroll
            for (int j = 0; j < 4; j++) {
                const int c = n0 - 512 + wc * 64 + j * 16 + cl;   // dv 0..511
#pragma unroll
                for (int r = 0; r < 4; r++) {
                    const int m = m0 + wr * 128 + i * 16 + rq + r;
                    Vt[(size_t)c * MROWS + m] = bf16_rne(acc[i][j][r]);
                }
            }
    } else {
        const bool isQ = (n0 < 256);
        unsigned short* dst = isQ ? Qb : Kb;
        const float sgn = isQ ? 1.f : -1.f;     // K downscaled
#pragma unroll
        for (int j = 0; j < 4; j++) {
            const int c = wc * 64 + j * 16 + cl;        // 0..255 within Q or K
            const float jj = (float)(c >> 1);
            const float sv = (2.f * jj + 0.4f * 256.f) * (1.f / (1.4f * 256.f));
            const float l2sv = __log2f(sv) * sgn * (1.f / 512.f);
            const float invf = exp2f(jj * (-LOG2_10000 / 128.f));
            const bool odd = (c & 1) != 0;
#pragma unroll
            for (int i = 0; i < 8; i++) {
#pragma unroll
                for (int r = 0; r < 4; r++) {
                    const int m = m0 + wr * 128 + i * 16 + rq + r;
                    const float s = (float)(m & (SEQ - 1));
                    const float x = acc[i][j][r];
                    const float p = __shfl_xor(x, 1, 64);   // partner col c^1
                    const float sc = exp2f(s * l2sv);
                    const float ang = s * invf;
                    const float sn = __sinf(ang), cs = __cosf(ang);
                    const float o = odd ? sc * (x * cs + p * sn)
                                        : sc * (x * cs - p * sn);
                    const unsigned short hv = bf16_rne(o);
                    dst[(size_t)m * DH + c] = hv;
                    if (!isQ) Kt[(size_t)c * MROWS + m] = hv;
                }
            }
        }
    }
}

// ---------------------------------------------------------------------------
// Kernel 2: per-chunk U_c^T = V^T diag(gamma^(C-i)) K, via bf16 MFMA.
// C[m=dv][n=dh] = sum_i Vt[dv][i] * (gamma^(C-i) Kt[dh][i]).
// Output Ut[b][c][dv 512][dh 256] fp32. Block = 128(dv) x 128(dh), K=128,
// 512 threads / 8 waves, wave 64x32. Grid = 4*32*4*2 = 1024.
// ---------------------------------------------------------------------------
__global__ __launch_bounds__(512, 1) void chunk_kv_kernel(
    const unsigned short* __restrict__ Kt, const unsigned short* __restrict__ Vt,
    float* __restrict__ Ut)
{
    __shared__ unsigned short As[128 * 32];   // Vt rows (dv) x i
    __shared__ unsigned short Bs[128 * 32];   // scaled Kt rows (dh) x i

    const int bid = blockIdx.x;      // 1024
    const int dht = bid & 1;
    const int vq  = (bid >> 1) & 3;
    const int c   = (bid >> 3) & 31;
    const int b   = bid >> 8;
    const int dh0 = dht * 128, dv0 = vq * 128;
    const int row0 = b * SEQ + c * CHUNK;

    const int t = threadIdx.x;
    const int w = t >> 6, lane = t & 63;
    const int wm = (w & 1) << 6;         // dv offset
    const int wn = (w >> 1) << 5;        // dh offset
    const int srow = lane >> 2, scol = (lane & 3) * 8;
    const int fr = lane & 15, fq = (lane >> 4) * 8;

    floatx4 acc[4][2];
#pragma unroll
    for (int i = 0; i < 4; i++)
#pragma unroll
        for (int j = 0; j < 2; j++) acc[i][j] = (floatx4)0.0f;

    const int kr = t >> 2, kc = (t & 3) * 8;   // B staging: 128 rows x 32 cols

    for (int i0 = 0; i0 < CHUNK; i0 += 32) {
        __syncthreads();
        gld16(&Vt[(size_t)(dv0 + w * 16 + srow) * MROWS + row0 + i0 + scol],
              &As[(w * 16) * 32]);
        {
            const unsigned short* src = &Kt[(size_t)(dh0 + kr) * MROWS + row0 + i0 + kc];
            ushort4 k0v = *(const ushort4*)src;
            ushort4 k1v = *(const ushort4*)(src + 4);
            float g = exp2f((float)(CHUNK - i0 - kc) * LOG2_GAMMA);  // gamma^(C-i)
            ushort4 h0, h1;
            h0.x = bf16_rne(b2f(k0v.x) * g); g *= GAMMA_INV;
            h0.y = bf16_rne(b2f(k0v.y) * g); g *= GAMMA_INV;
            h0.z = bf16_rne(b2f(k0v.z) * g); g *= GAMMA_INV;
            h0.w = bf16_rne(b2f(k0v.w) * g); g *= GAMMA_INV;
            h1.x = bf16_rne(b2f(k1v.x) * g); g *= GAMMA_INV;
            h1.y = bf16_rne(b2f(k1v.y) * g); g *= GAMMA_INV;
            h1.z = bf16_rne(b2f(k1v.z) * g); g *= GAMMA_INV;
            h1.w = bf16_rne(b2f(k1v.w) * g);
            *(ushort4*)&Bs[kr * 32 + kc] = h0;
            *(ushort4*)&Bs[kr * 32 + kc + 4] = h1;
        }
        __syncthreads();
        short8 a[4], bb[2];
#pragma unroll
        for (int i = 0; i < 4; i++)
            a[i] = *(const short8*)&As[(wm + i * 16 + fr) * 32 + fq];
#pragma unroll
        for (int j = 0; j < 2; j++)
            bb[j] = *(const short8*)&Bs[(wn + j * 16 + fr) * 32 + fq];
#pragma unroll
        for (int i = 0; i < 4; i++)
#pragma unroll
            for (int j = 0; j < 2; j++)
                acc[i][j] = __builtin_amdgcn_mfma_f32_16x16x32_bf16(a[i], bb[j], acc[i][j], 0, 0, 0);
    }

    // store: C[m=dv][n=dh] -> Ut[((b*32+c)*512 + dv0+m)*256 + dh0+n]
    const int cl = lane & 15, rq = (lane >> 4) << 2;
    const size_t ubase = ((size_t)(b * NCH + c) * DV + dv0) * DH + dh0;
#pragma unroll
    for (int i = 0; i < 4; i++)
#pragma unroll
        for (int j = 0; j < 2; j++) {
            const int n = wn + j * 16 + cl;
#pragma unroll
            for (int r = 0; r < 4; r++) {
                const int m = wm + i * 16 + rq + r;
                Ut[ubase + (size_t)m * DH + n] = acc[i][j][r];
            }
        }
}

// ---------------------------------------------------------------------------
// Kernel 3: exclusive scan over chunks; emits bf16 state Sb[c] = S_c
// (state BEFORE chunk c), layout [b][c][dv][dh] (B-operand-ready).
// ---------------------------------------------------------------------------
__global__ __launch_bounds__(256) void scan_kernel(
    const float* __restrict__ Ut, unsigned short* __restrict__ Sb)
{
    const int t = blockIdx.x * 256 + threadIdx.x;   // 0..524287
    const int b = t >> 17;                          // DV*DH = 131072
    const int r = t & 131071;
    const float gC = exp2f((float)CHUNK * LOG2_GAMMA);
    float s = 0.f;
    const size_t base = (size_t)b * NCH * 131072 + r;
    for (int c = 0; c < NCH; c++) {
        const size_t off = base + (size_t)c * 131072;
        const float u = Ut[off];
        Sb[off] = bf16_rne(s);
        s = gC * s + u;
    }
}

// ---------------------------------------------------------------------------
// Kernel 4: O = (tril(QK^T) .* gamma^(i-j)) @ V  +  (gamma^i Q) @ S_c^T.
// Full bf16 MFMA, 512 threads = 8 waves, wave 64x32. BK=64 in phases 1/3.
// Block = (b, chunk, dv-quarter): 128(i) x 128(dv) output. Grid = 512.
// ---------------------------------------------------------------------------
__global__ __launch_bounds__(512, 1) void out_mfma_kernel(
    const unsigned short* __restrict__ Qb, const unsigned short* __restrict__ Kb,
    const unsigned short* __restrict__ Vt, const unsigned short* __restrict__ Sb,
    float* __restrict__ out)
{
    __shared__ unsigned short Pa[128 * 136];   // P bf16, row stride 136 (pad)
    __shared__ unsigned short As[2 * 128 * 32];
    __shared__ unsigned short Bs[2 * 128 * 32];

    const int bid = blockIdx.x;      // 512
    const int vq = bid & 3;
    const int c  = (bid >> 2) & 31;
    const int b  = bid >> 7;
    const int dv0 = vq * 128;
    const int row0 = b * SEQ + c * CHUNK;

    const int t = threadIdx.x;
    const int w = t >> 6, lane = t & 63;
    const int wm = (w & 1) << 6;         // 0,64
    const int wn = (w >> 1) << 5;        // 0,32,64,96
    const int fr = lane & 15, fq = (lane >> 4) * 8;
    const int cl = lane & 15, rq = (lane >> 4) << 2;
    const int srow = lane >> 2, scol = (lane & 3) * 8;

    floatx4 acc[4][2];
#pragma unroll
    for (int i = 0; i < 4; i++)
#pragma unroll
        for (int j = 0; j < 2; j++) acc[i][j] = (floatx4)0.0f;

    // ---------------- phase 1: P = Q K^T (BK=64) ----------------
    for (int d0 = 0; d0 < DH; d0 += 64) {
        __syncthreads();
        gld16(&Qb[(size_t)(row0 + w * 16 + srow) * DH + d0 + scol], &As[(w * 16) * 32]);
        gld16(&Qb[(size_t)(row0 + w * 16 + srow) * DH + d0 + 32 + scol], &As[4096 + (w * 16) * 32]);
        gld16(&Kb[(size_t)(row0 + w * 16 + srow) * DH + d0 + scol], &Bs[(w * 16) * 32]);
        gld16(&Kb[(size_t)(row0 + w * 16 + srow) * DH + d0 + 32 + scol], &Bs[4096 + (w * 16) * 32]);
        __syncthreads();
#pragma nounroll
        for (int s = 0; s < 2; s++) {
            short8 a[4], bb[2];
#pragma unroll
            for (int i = 0; i < 4; i++)
                a[i] = *(const short8*)&As[s * 4096 + (wm + i * 16 + fr) * 32 + fq];
#pragma unroll
            for (int j = 0; j < 2; j++)
                bb[j] = *(const short8*)&Bs[s * 4096 + (wn + j * 16 + fr) * 32 + fq];
#pragma unroll
            for (int i = 0; i < 4; i++)
#pragma unroll
                for (int j = 0; j < 2; j++)
                    acc[i][j] = __builtin_amdgcn_mfma_f32_16x16x32_bf16(a[i], bb[j], acc[i][j], 0, 0, 0);
        }
    }

    // decay mask + bf16 -> Pa[i][j] (i = q row in chunk, j = k row)
#pragma unroll
    for (int i = 0; i < 4; i++)
#pragma unroll
        for (int j = 0; j < 2; j++) {
            const int jj = wn + j * 16 + cl;
#pragma unroll
            for (int r = 0; r < 4; r++) {
                const int ii = wm + i * 16 + rq + r;
                const int diff = ii - jj;
                const float v = (diff >= 0) ? acc[i][j][r] * exp2f((float)diff * LOG2_GAMMA) : 0.f;
                Pa[ii * 136 + jj] = bf16_rne(v);
            }
            acc[i][j] = (floatx4)0.0f;     // reset for O accumulation
        }

    // ---------------- phase 2: acc = P @ V (BK=64, K=128 total) ----------
    for (int k0 = 0; k0 < CHUNK; k0 += 64) {
        __syncthreads();   // first iter: Pa visible; later: Bs reads done
        gld16(&Vt[(size_t)(dv0 + w * 16 + srow) * MROWS + row0 + k0 + scol], &Bs[(w * 16) * 32]);
        gld16(&Vt[(size_t)(dv0 + w * 16 + srow) * MROWS + row0 + k0 + 32 + scol], &Bs[4096 + (w * 16) * 32]);
        __syncthreads();
#pragma nounroll
        for (int s = 0; s < 2; s++) {
            short8 a[4], bb[2];
#pragma unroll
            for (int i = 0; i < 4; i++)
                a[i] = *(const short8*)&Pa[(wm + i * 16 + fr) * 136 + k0 + s * 32 + fq];
#pragma unroll
            for (int j = 0; j < 2; j++)
                bb[j] = *(const short8*)&Bs[s * 4096 + (wn + j * 16 + fr) * 32 + fq];
#pragma unroll
            for (int i = 0; i < 4; i++)
#pragma unroll
                for (int j = 0; j < 2; j++)
                    acc[i][j] = __builtin_amdgcn_mfma_f32_16x16x32_bf16(a[i], bb[j], acc[i][j], 0, 0, 0);
        }
    }

    // ---------------- phase 3: acc += (gamma^i Q) @ Sb (BK=64) ------------
    const size_t sbbase = ((size_t)(b * NCH + c) * DV + dv0) * DH;
    const int xr = t >> 2, xc = (t & 3) * 8;     // A staging: 128 rows x 32 cols
    const float gx = exp2f((float)xr * LOG2_GAMMA);   // gamma^i
    for (int d0 = 0; d0 < DH; d0 += 64) {
        __syncthreads();
#pragma unroll
        for (int s = 0; s < 2; s++) {
            const unsigned short* src = &Qb[(size_t)(row0 + xr) * DH + d0 + s * 32 + xc];
            ushort4 q0 = *(const ushort4*)src;
            ushort4 q1 = *(const ushort4*)(src + 4);
            ushort4 h0, h1;
            h0.x = bf16_rne(b2f(q0.x) * gx); h0.y = bf16_rne(b2f(q0.y) * gx);
            h0.z = bf16_rne(b2f(q0.z) * gx); h0.w = bf16_rne(b2f(q0.w) * gx);
            h1.x = bf16_rne(b2f(q1.x) * gx); h1.y = bf16_rne(b2f(q1.y) * gx);
            h1.z = bf16_rne(b2f(q1.z) * gx); h1.w = bf16_rne(b2f(q1.w) * gx);
            *(ushort4*)&As[s * 4096 + xr * 32 + xc] = h0;
            *(ushort4*)&As[s * 4096 + xr * 32 + xc + 4] = h1;
        }
        gld16(&Sb[sbbase + (size_t)(w * 16 + srow) * DH + d0 + scol], &Bs[(w * 16) * 32]);
        gld16(&Sb[sbbase + (size_t)(w * 16 + srow) * DH + d0 + 32 + scol], &Bs[4096 + (w * 16) * 32]);
        __syncthreads();
#pragma nounroll
        for (int s = 0; s < 2; s++) {
            short8 a[4], bb[2];
#pragma unroll
            for (int i = 0; i < 4; i++)
                a[i] = *(const short8*)&As[s * 4096 + (wm + i * 16 + fr) * 32 + fq];
#pragma unroll
            for (int j = 0; j < 2; j++)
                bb[j] = *(const short8*)&Bs[s * 4096 + (wn + j * 16 + fr) * 32 + fq];
#pragma unroll
            for (int i = 0; i < 4; i++)
#pragma unroll
                for (int j = 0; j < 2; j++)
                    acc[i][j] = __builtin_amdgcn_mfma_f32_16x16x32_bf16(a[i], bb[j], acc[i][j], 0, 0, 0);
        }
    }

    // epilogue: fp32 store
#pragma unroll
    for (int i = 0; i < 4; i++)
#pragma unroll
        for (int j = 0; j < 2; j++) {
            const int dv = dv0 + wn + j * 16 + cl;
#pragma unroll
            for (int r = 0; r < 4; r++) {
                const int m = row0 + wm + i * 16 + rq + r;
                out[(size_t)m * DV + dv] = acc[i][j][r];
            }
        }
}

// ---------------------------------------------------------------------------
extern "C" void kernel_launch(void* const* d_in, const int* in_sizes, int n_in,
                              void* d_out, int out_size, void* d_ws, size_t ws_size,
                              hipStream_t stream) {
    const float* X  = (const float*)d_in[0];
    const float* WQ = (const float*)d_in[1];
    const float* WK = (const float*)d_in[2];
    const float* WV = (const float*)d_in[3];
    float* out = (float*)d_out;

    // Workspace layout (bf16 unless noted):
    //   Qb 8.4 | Kb 8.4 | Kt 8.4 | Vt 16.8 | Sb 33.5 | Ut fp32 67.1 | Bt 4.2
    //   Xb (67.1) OVERLAPS Ut (Xb dead after qkv; Ut written after). ~147 MB.
    char* ws = (char*)d_ws;
    unsigned short* Qb = (unsigned short*)ws;
    unsigned short* Kb = Qb + (size_t)MROWS * DH;
    unsigned short* Kt = Kb + (size_t)MROWS * DH;
    unsigned short* Vt = Kt + (size_t)MROWS * DH;
    unsigned short* Sb = Vt + (size_t)MROWS * DV;
    float*          Ut = (float*)(Sb + (size_t)NB * NCH * DV * DH);
    unsigned short* Xb = (unsigned short*)Ut;       // overlap
    unsigned short* Bt = (unsigned short*)(Ut + (size_t)NB * NCH * DV * DH);

    xcvt_kernel<<<(MROWS * HID / 4) / 256, 256, 0, stream>>>(X, Xb);
    wcvt_kernel<<<512, 256, 0, stream>>>(WQ, WK, WV, Bt);
    qkv_mfma_kernel<<<256, 512, 0, stream>>>(Xb, Bt, Qb, Kb, Kt, Vt);
    chunk_kv_kernel<<<1024, 512, 0, stream>>>(Kt, Vt, Ut);
    scan_kernel<<<2048, 256, 0, stream>>>(Ut, Sb);
    out_mfma_kernel<<<512, 512, 0, stream>>>(Qb, Kb, Vt, Sb, out);
}

// Round 7
// 363.575 us; speedup vs baseline: 1.0113x; 1.0113x over previous
//
#include <hip/hip_runtime.h>
#include <math.h>

#define NB 4
#define SEQ 4096
#define HID 2048
#define DH 256
#define DV 512
#define CHUNK 128
#define NCH 32                  // SEQ/CHUNK
#define MROWS (NB * SEQ)        // 16384
#define GAMMA 0.96875f
#define GAMMA_INV 1.0322580645161290f
// log2(0.96875)
#define LOG2_GAMMA (-0.045803689613124794f)
// log2(10000)
#define LOG2_10000 13.287712379549449f

typedef __attribute__((ext_vector_type(8))) short short8;
typedef __attribute__((ext_vector_type(4))) float floatx4;

// ---------------------------------------------------------------------------
// helpers
// ---------------------------------------------------------------------------
__device__ __forceinline__ unsigned short bf16_rne(float v) {
    unsigned int u = __float_as_uint(v);
    u += 0x7fff + ((u >> 16) & 1);
    return (unsigned short)(u >> 16);
}
__device__ __forceinline__ float b2f(unsigned short h) {
    return __uint_as_float((unsigned int)h << 16);
}

// async global->LDS, 16 bytes per lane. LDS dest = wave-uniform base + lane*16.
__device__ __forceinline__ void gld16(const void* g, void* l) {
    __builtin_amdgcn_global_load_lds(
        reinterpret_cast<const __attribute__((address_space(1))) unsigned int*>(
            reinterpret_cast<uintptr_t>(g)),
        reinterpret_cast<__attribute__((address_space(3))) unsigned int*>(
            reinterpret_cast<uintptr_t>(l)),
        16, 0, 0);
}

// ---------------------------------------------------------------------------
// Kernel 0a: X fp32 -> bf16 row-major [M][K].
// ---------------------------------------------------------------------------
__global__ __launch_bounds__(256) void xcvt_kernel(
    const float* __restrict__ X, unsigned short* __restrict__ Xb)
{
    const int i = blockIdx.x * 256 + threadIdx.x;   // one float4 per thread
    float4 x = ((const float4*)X)[i];
    ushort4 h;
    h.x = bf16_rne(x.x); h.y = bf16_rne(x.y);
    h.z = bf16_rne(x.z); h.w = bf16_rne(x.w);
    ((ushort4*)Xb)[i] = h;
}

// ---------------------------------------------------------------------------
// Kernel 0b: W_Q|W_K|W_V fp32 [K][Nregion] -> transposed packed bf16 Bt[n][k].
// ---------------------------------------------------------------------------
__global__ __launch_bounds__(256) void wcvt_kernel(
    const float* __restrict__ WQ, const float* __restrict__ WK,
    const float* __restrict__ WV, unsigned short* __restrict__ Bt)
{
    __shared__ unsigned short sh[64][65];
    const int bid = blockIdx.x;         // 32 k-tiles * 16 n-tiles
    const int kt = bid & 31;
    const int ntile = bid >> 5;
    const int k0 = kt * 64, n0 = ntile * 64;

    const float* W; int ld, nl0;
    if (n0 < 256)      { W = WQ; ld = DH; nl0 = n0; }
    else if (n0 < 512) { W = WK; ld = DH; nl0 = n0 - 256; }
    else               { W = WV; ld = DV; nl0 = n0 - 512; }

    const int t = threadIdx.x;
#pragma unroll
    for (int p = 0; p < 4; p++) {
        const int kl = (t >> 4) + p * 16;
        const int ng = (t & 15) * 4;
        float4 w = *(const float4*)&W[(size_t)(k0 + kl) * ld + nl0 + ng];
        sh[kl][ng + 0] = bf16_rne(w.x);
        sh[kl][ng + 1] = bf16_rne(w.y);
        sh[kl][ng + 2] = bf16_rne(w.z);
        sh[kl][ng + 3] = bf16_rne(w.w);
    }
    __syncthreads();
#pragma unroll
    for (int p = 0; p < 4; p++) {
        const int nl = (t >> 4) + p * 16;
        const int kg = (t & 15) * 4;
        ushort4 h;
        h.x = sh[kg + 0][nl]; h.y = sh[kg + 1][nl];
        h.z = sh[kg + 2][nl]; h.w = sh[kg + 3][nl];
        *(ushort4*)&Bt[(size_t)(n0 + nl) * HID + k0 + kg] = h;
    }
}

// ---------------------------------------------------------------------------
// Kernel 1: QKV projection, bf16 MFMA + xPos epilogue.
// M=16384, N=1024, K=2048.
// ROUND 3 (kept): 256x256 tile, 8-wave, 4-phase pipeline, drain-per-tile.
// 99us / 28% MfmaUtil — matches m218 "phase-split with drain0 == 2-phase";
// counted-vmcnt needs >=3 buffers (future work). Untouched this round.
// ---------------------------------------------------------------------------
__global__ __launch_bounds__(512, 2) void qkv_mfma_kernel(
    const unsigned short* __restrict__ Xb, const unsigned short* __restrict__ Bt,
    unsigned short* __restrict__ Qb, unsigned short* __restrict__ Kb,
    unsigned short* __restrict__ Kt, unsigned short* __restrict__ Vt)
{
    __shared__ unsigned short lds[2 * 32768];   // [buf][A 256x64 | B 256x64]

    // XCD-aware map: same-XCD blocks share the same A-panel (mt), 4 n-tiles.
    const int bid = blockIdx.x;          // 256 blocks
    const int xcd = bid & 7;
    const int idx = bid >> 3;            // 0..31
    const int mt  = (xcd << 3) | (idx >> 2);   // 64 m-tiles
    const int nt  = idx & 3;             // 4 n-tiles
    const int m0 = mt * 256, n0 = nt * 256;

    const int t = threadIdx.x;
    const int w = t >> 6, lane = t & 63;   // 8 waves
    const int wr = w >> 2;               // 0..1: row half (128 rows)
    const int wc = w & 3;                // 0..3: col quarter (64 cols)

    floatx4 acc[8][4];
#pragma unroll
    for (int i = 0; i < 8; i++)
#pragma unroll
        for (int j = 0; j < 4; j++) acc[i][j] = (floatx4)0.0f;

    // staging addressing: per gld16, lane l -> row rl = l>>3, LDS slot l&7
    // holding global slot (l&7)^rl  (XOR swizzle, row&7 == rl).
    const int rl = lane >> 3;
    const int sg = (lane & 7) ^ rl;

    // fragment addressing: row r, slot_g = (s<<2)|g; LDS slot = slot_g ^ (r&7)
    const int fr = lane & 15, g = lane >> 4;
    const int x7 = fr & 7;
    const int soff0 = ((g ^ x7) << 3);          // s=0, in ushort units
    const int soff1 = (((4 | g) ^ x7) << 3);    // s=1

#define STAGE_HT(isB, h, dbuf, kt)                                            \
    {                                                                         \
        const unsigned short* gsrc =                                          \
            ((isB) ? Bt + (size_t)(n0 + (h) * 128 + w * 16 + rl) * HID        \
                   : Xb + (size_t)(m0 + (h) * 128 + w * 16 + rl) * HID)       \
            + (size_t)(kt) * 64 + sg * 8;                                     \
        unsigned short* ldst = &lds[(dbuf) * 32768 + ((isB) ? 16384 : 0)      \
                                    + ((h) * 128 + w * 16) * 64];             \
        gld16(gsrc, ldst);                                                    \
        gld16(gsrc + (size_t)8 * HID, ldst + 8 * 64);                         \
    }

#define READ_A(ih)                                                            \
    _Pragma("unroll")                                                         \
    for (int i2 = 0; i2 < 4; i2++) {                                          \
        const int row = wr * 128 + ((ih) * 4 + i2) * 16 + fr;                 \
        ah[i2][0] = *(const short8*)&lds[cb + row * 64 + soff0];              \
        ah[i2][1] = *(const short8*)&lds[cb + row * 64 + soff1];              \
    }

#define READ_B(jh)                                                            \
    _Pragma("unroll")                                                         \
    for (int j2 = 0; j2 < 2; j2++) {                                          \
        const int row = wc * 64 + ((jh) * 2 + j2) * 16 + fr;                  \
        bh[(jh) * 2 + j2][0] = *(const short8*)&lds[cb + 16384 + row * 64 + soff0]; \
        bh[(jh) * 2 + j2][1] = *(const short8*)&lds[cb + 16384 + row * 64 + soff1]; \
    }

#define MFMA16(ib, jb)                                                        \
    _Pragma("unroll")                                                         \
    for (int i2 = 0; i2 < 4; i2++)                                            \
        _Pragma("unroll")                                                     \
        for (int j2 = 0; j2 < 2; j2++) {                                      \
            acc[(ib) + i2][(jb) + j2] = __builtin_amdgcn_mfma_f32_16x16x32_bf16( \
                ah[i2][0], bh[(jb) + j2][0], acc[(ib) + i2][(jb) + j2], 0, 0, 0); \
            acc[(ib) + i2][(jb) + j2] = __builtin_amdgcn_mfma_f32_16x16x32_bf16( \
                ah[i2][1], bh[(jb) + j2][1], acc[(ib) + i2][(jb) + j2], 0, 0, 0); \
        }

    // prologue: stage K-tile 0 into buf0, drain, align.
    STAGE_HT(0, 0, 0, 0); STAGE_HT(0, 1, 0, 0);
    STAGE_HT(1, 0, 0, 0); STAGE_HT(1, 1, 0, 0);
    asm volatile("s_waitcnt vmcnt(0)" ::: "memory");
    __builtin_amdgcn_s_barrier();
    __builtin_amdgcn_sched_barrier(0);

    int cur = 0;
    for (int kt = 0; kt < 32; ++kt) {
        const int nxt = cur ^ 1;
        if (kt + 1 < 32) {                 // stage next K-tile into idle buffer
            STAGE_HT(0, 0, nxt, kt + 1); STAGE_HT(0, 1, nxt, kt + 1);
            STAGE_HT(1, 0, nxt, kt + 1); STAGE_HT(1, 1, nxt, kt + 1);
        }
        const int cb = cur * 32768;
        short8 ah[4][2], bh[4][2];

        // ---- phase 1: C-quadrant (i 0-3, j 0-1), K=64 ----
        READ_A(0); READ_B(0);
        __builtin_amdgcn_s_barrier();
        __builtin_amdgcn_sched_barrier(0);
        __builtin_amdgcn_s_setprio(1);
        MFMA16(0, 0);
        __builtin_amdgcn_s_setprio(0);
        __builtin_amdgcn_s_barrier();
        __builtin_amdgcn_sched_barrier(0);

        // ---- phase 2: (i 0-3, j 2-3) ----
        READ_B(1);
        __builtin_amdgcn_s_barrier();
        __builtin_amdgcn_sched_barrier(0);
        __builtin_amdgcn_s_setprio(1);
        MFMA16(0, 2);
        __builtin_amdgcn_s_setprio(0);
        __builtin_amdgcn_s_barrier();
        __builtin_amdgcn_sched_barrier(0);

        // ---- phase 3: (i 4-7, j 0-1) ----
        READ_A(1);
        __builtin_amdgcn_s_barrier();
        __builtin_amdgcn_sched_barrier(0);
        __builtin_amdgcn_s_setprio(1);
        MFMA16(4, 0);
        __builtin_amdgcn_s_setprio(0);
        __builtin_amdgcn_s_barrier();
        __builtin_amdgcn_sched_barrier(0);

        // ---- phase 4: (i 4-7, j 2-3), then iter-end drain+align ----
        __builtin_amdgcn_s_setprio(1);
        MFMA16(4, 2);
        __builtin_amdgcn_s_setprio(0);
        asm volatile("s_waitcnt vmcnt(0)" ::: "memory");   // next-tile loads landed
        __builtin_amdgcn_s_barrier();
        __builtin_amdgcn_sched_barrier(0);
        cur = nxt;
    }
#undef STAGE_HT
#undef READ_A
#undef READ_B
#undef MFMA16

    // epilogue. C/D layout: col = lane&15, row = (lane>>4)*4 + reg.
    const int cl = lane & 15, rq = (lane >> 4) << 2;
    if (n0 >= 512) {
#pragma unroll
        for (int i = 0; i < 8; i++)
#pragma unroll
            for (int j = 0; j < 4; j++) {
                const int c = n0 - 512 + wc * 64 + j * 16 + cl;   // dv 0..511
#pragma unroll
                for (int r = 0; r < 4; r++) {
                    const int m = m0 + wr * 128 + i * 16 + rq + r;
                    Vt[(size_t)c * MROWS + m] = bf16_rne(acc[i][j][r]);
                }
            }
    } else {
        const bool isQ = (n0 < 256);
        unsigned short* dst = isQ ? Qb : Kb;
        const float sgn = isQ ? 1.f : -1.f;     // K downscaled
#pragma unroll
        for (int j = 0; j < 4; j++) {
            const int c = wc * 64 + j * 16 + cl;        // 0..255 within Q or K
            const float jj = (float)(c >> 1);
            const float sv = (2.f * jj + 0.4f * 256.f) * (1.f / (1.4f * 256.f));
            const float l2sv = __log2f(sv) * sgn * (1.f / 512.f);
            const float invf = exp2f(jj * (-LOG2_10000 / 128.f));
            const bool odd = (c & 1) != 0;
#pragma unroll
            for (int i = 0; i < 8; i++) {
#pragma unroll
                for (int r = 0; r < 4; r++) {
                    const int m = m0 + wr * 128 + i * 16 + rq + r;
                    const float s = (float)(m & (SEQ - 1));
                    const float x = acc[i][j][r];
                    const float p = __shfl_xor(x, 1, 64);   // partner col c^1
                    const float sc = exp2f(s * l2sv);
                    const float ang = s * invf;
                    const float sn = __sinf(ang), cs = __cosf(ang);
                    const float o = odd ? sc * (x * cs + p * sn)
                                        : sc * (x * cs - p * sn);
                    const unsigned short hv = bf16_rne(o);
                    dst[(size_t)m * DH + c] = hv;
                    if (!isQ) Kt[(size_t)c * MROWS + m] = hv;
                }
            }
        }
    }
}

// ---------------------------------------------------------------------------
// Kernel 2: per-chunk U_c^T = V^T diag(gamma^(C-i)) K, via bf16 MFMA.
// ROUND 5: full K=128 staged ONCE (As/Bs 128x128, 32KB each), 2 barriers
// total (was 8), slot-16 XOR swizzle (source-swizzled gld16 for A,
// register-staged swizzled ds_write for scaled B) -> conflict-free reads
// (was 8-way). Same MFMA order -> bit-identical results.
// Block = 128(dv) x 128(dh), 512 thr / 8 waves, wave 64x32. Grid = 1024.
// ---------------------------------------------------------------------------
__global__ __launch_bounds__(512, 2) void chunk_kv_kernel(
    const unsigned short* __restrict__ Kt, const unsigned short* __restrict__ Vt,
    float* __restrict__ Ut)
{
    __shared__ unsigned short As[128 * 128];   // Vt tile, slot16-swizzled
    __shared__ unsigned short Bs[128 * 128];   // scaled Kt tile, slot16-swizzled

    const int bid = blockIdx.x;      // 1024
    const int dht = bid & 1;
    const int vq  = (bid >> 1) & 3;
    const int c   = (bid >> 3) & 31;
    const int b   = bid >> 8;
    const int dh0 = dht * 128, dv0 = vq * 128;
    const int row0 = b * SEQ + c * CHUNK;

    const int t = threadIdx.x;
    const int w = t >> 6, lane = t & 63;
    const int wm = (w & 1) << 6;         // dv offset
    const int wn = (w >> 1) << 5;        // dh offset
    const int fr = lane & 15, g = lane >> 4;

    floatx4 acc[4][2];
#pragma unroll
    for (int i = 0; i < 4; i++)
#pragma unroll
        for (int j = 0; j < 2; j++) acc[i][j] = (floatx4)0.0f;

    // ---- stage A (Vt): 4 gld16/wave, rows w*16+q*4+(lane>>4), slot lane&15.
    // LDS[row][slot] = global[row][slot ^ (row&15)] via per-lane source addr.
    {
        const int ar = lane >> 4, asl = lane & 15;
#pragma unroll
        for (int q = 0; q < 4; q++) {
            const int row = w * 16 + q * 4 + ar;
            const int ssl = asl ^ (row & 15);
            gld16(&Vt[(size_t)(dv0 + row) * MROWS + row0 + ssl * 8],
                  &As[(w * 16 + q * 4) * 128]);
        }
    }
    // ---- stage B (scaled Kt): per thread row kr = t>>2, 4 col-groups of 8.
    {
        const int kr = t >> 2, kc4 = t & 3;
#pragma unroll
        for (int p = 0; p < 4; p++) {
            const int col = kc4 * 8 + p * 32;
            const unsigned short* src = &Kt[(size_t)(dh0 + kr) * MROWS + row0 + col];
            ushort4 k0v = *(const ushort4*)src;
            ushort4 k1v = *(const ushort4*)(src + 4);
            float gsc = exp2f((float)(CHUNK - col) * LOG2_GAMMA);  // gamma^(C-i)
            ushort4 h0, h1;
            h0.x = bf16_rne(b2f(k0v.x) * gsc); gsc *= GAMMA_INV;
            h0.y = bf16_rne(b2f(k0v.y) * gsc); gsc *= GAMMA_INV;
            h0.z = bf16_rne(b2f(k0v.z) * gsc); gsc *= GAMMA_INV;
            h0.w = bf16_rne(b2f(k0v.w) * gsc); gsc *= GAMMA_INV;
            h1.x = bf16_rne(b2f(k1v.x) * gsc); gsc *= GAMMA_INV;
            h1.y = bf16_rne(b2f(k1v.y) * gsc); gsc *= GAMMA_INV;
            h1.z = bf16_rne(b2f(k1v.z) * gsc); gsc *= GAMMA_INV;
            h1.w = bf16_rne(b2f(k1v.w) * gsc);
            const int wsl = (kc4 + p * 4) ^ (kr & 15);   // cs = col>>3
            *(ushort4*)&Bs[kr * 128 + wsl * 8] = h0;
            *(ushort4*)&Bs[kr * 128 + wsl * 8 + 4] = h1;
        }
    }
    __syncthreads();

#pragma nounroll
    for (int s = 0; s < 4; s++) {
        short8 a[4], bb[2];
#pragma unroll
        for (int i = 0; i < 4; i++)
            a[i] = *(const short8*)&As[(wm + i * 16 + fr) * 128
                                       + (((s * 4 + g) ^ fr) << 3)];
#pragma unroll
        for (int j = 0; j < 2; j++)
            bb[j] = *(const short8*)&Bs[(wn + j * 16 + fr) * 128
                                        + (((s * 4 + g) ^ fr) << 3)];
#pragma unroll
        for (int i = 0; i < 4; i++)
#pragma unroll
            for (int j = 0; j < 2; j++)
                acc[i][j] = __builtin_amdgcn_mfma_f32_16x16x32_bf16(a[i], bb[j], acc[i][j], 0, 0, 0);
    }

    // store: C[m=dv][n=dh] -> Ut[((b*32+c)*512 + dv0+m)*256 + dh0+n]
    const int cl = lane & 15, rq = (lane >> 4) << 2;
    const size_t ubase = ((size_t)(b * NCH + c) * DV + dv0) * DH + dh0;
#pragma unroll
    for (int i = 0; i < 4; i++)
#pragma unroll
        for (int j = 0; j < 2; j++) {
            const int n = wn + j * 16 + cl;
#pragma unroll
            for (int r = 0; r < 4; r++) {
                const int m = wm + i * 16 + rq + r;
                Ut[ubase + (size_t)m * DH + n] = acc[i][j][r];
            }
        }
}

// ---------------------------------------------------------------------------
// Kernel 3: exclusive scan over chunks; emits bf16 state Sb[c] = S_c
// (state BEFORE chunk c), layout [b][c][dv][dh] (B-operand-ready).
// ---------------------------------------------------------------------------
__global__ __launch_bounds__(256) void scan_kernel(
    const float* __restrict__ Ut, unsigned short* __restrict__ Sb)
{
    const int t = blockIdx.x * 256 + threadIdx.x;   // 0..524287
    const int b = t >> 17;                          // DV*DH = 131072
    const int r = t & 131071;
    const float gC = exp2f((float)CHUNK * LOG2_GAMMA);
    float s = 0.f;
    const size_t base = (size_t)b * NCH * 131072 + r;
    for (int c = 0; c < NCH; c++) {
        const size_t off = base + (size_t)c * 131072;
        const float u = Ut[off];
        Sb[off] = bf16_rne(s);
        s = gC * s + u;
    }
}

// ---------------------------------------------------------------------------
// Kernel 4: O = (tril(QK^T) .* gamma^(i-j)) @ V  +  (gamma^i Q) @ S_c^T.
// ROUND 5: As/Bs -> single [128][64] slot-8 XOR-swizzled layout (128B rows)
// for all three phases: fragment reads conflict-free (was 8-way). Barrier
// structure unchanged; LDS still 66KB -> 2 blocks/CU. Pa already 2-way.
// 512 threads = 8 waves, wave 64x32. Grid = 512.
// ---------------------------------------------------------------------------
__global__ __launch_bounds__(512, 1) void out_mfma_kernel(
    const unsigned short* __restrict__ Qb, const unsigned short* __restrict__ Kb,
    const unsigned short* __restrict__ Vt, const unsigned short* __restrict__ Sb,
    float* __restrict__ out)
{
    __shared__ unsigned short Pa[128 * 136];   // P bf16, row stride 136 (pad)
    __shared__ unsigned short As[128 * 64];    // slot8-swizzled
    __shared__ unsigned short Bs[128 * 64];    // slot8-swizzled

    const int bid = blockIdx.x;      // 512
    const int vq = bid & 3;
    const int c  = (bid >> 2) & 31;
    const int b  = bid >> 7;
    const int dv0 = vq * 128;
    const int row0 = b * SEQ + c * CHUNK;

    const int t = threadIdx.x;
    const int w = t >> 6, lane = t & 63;
    const int wm = (w & 1) << 6;         // 0,64
    const int wn = (w >> 1) << 5;        // 0,32,64,96
    const int fr = lane & 15, g = lane >> 4, fq = g * 8;
    const int cl = lane & 15, rq = (lane >> 4) << 2;
    // gld16 staging: 8 rows x 128B per load; LDS slot l&7 holds global
    // slot (l&7)^(row&7), row = base + q*8 + (l>>3).
    const int rl8 = lane >> 3, sl8 = lane & 7;
    const int ssl8 = sl8 ^ rl8;
    const int x7 = fr & 7;

    floatx4 acc[4][2];
#pragma unroll
    for (int i = 0; i < 4; i++)
#pragma unroll
        for (int j = 0; j < 2; j++) acc[i][j] = (floatx4)0.0f;

    // ---------------- phase 1: P = Q K^T (BK=64) ----------------
    for (int d0 = 0; d0 < DH; d0 += 64) {
        __syncthreads();
#pragma unroll
        for (int q = 0; q < 2; q++) {
            const int row = w * 16 + q * 8 + rl8;
            gld16(&Qb[(size_t)(row0 + row) * DH + d0 + ssl8 * 8],
                  &As[(w * 16 + q * 8) * 64]);
            gld16(&Kb[(size_t)(row0 + row) * DH + d0 + ssl8 * 8],
                  &Bs[(w * 16 + q * 8) * 64]);
        }
        __syncthreads();
#pragma nounroll
        for (int s = 0; s < 2; s++) {
            short8 a[4], bb[2];
#pragma unroll
            for (int i = 0; i < 4; i++)
                a[i] = *(const short8*)&As[(wm + i * 16 + fr) * 64
                                           + (((s * 4 + g) ^ x7) << 3)];
#pragma unroll
            for (int j = 0; j < 2; j++)
                bb[j] = *(const short8*)&Bs[(wn + j * 16 + fr) * 64
                                            + (((s * 4 + g) ^ x7) << 3)];
#pragma unroll
            for (int i = 0; i < 4; i++)
#pragma unroll
                for (int j = 0; j < 2; j++)
                    acc[i][j] = __builtin_amdgcn_mfma_f32_16x16x32_bf16(a[i], bb[j], acc[i][j], 0, 0, 0);
        }
    }

    // decay mask + bf16 -> Pa[i][j] (i = q row in chunk, j = k row)
#pragma unroll
    for (int i = 0; i < 4; i++)
#pragma unroll
        for (int j = 0; j < 2; j++) {
            const int jj = wn + j * 16 + cl;
#pragma unroll
            for (int r = 0; r < 4; r++) {
                const int ii = wm + i * 16 + rq + r;
                const int diff = ii - jj;
                const float v = (diff >= 0) ? acc[i][j][r] * exp2f((float)diff * LOG2_GAMMA) : 0.f;
                Pa[ii * 136 + jj] = bf16_rne(v);
            }
            acc[i][j] = (floatx4)0.0f;     // reset for O accumulation
        }

    // ---------------- phase 2: acc = P @ V (BK=64, K=128 total) ----------
    for (int k0 = 0; k0 < CHUNK; k0 += 64) {
        __syncthreads();   // first iter: Pa visible; later: Bs reads done
#pragma unroll
        for (int q = 0; q < 2; q++) {
            const int row = w * 16 + q * 8 + rl8;
            gld16(&Vt[(size_t)(dv0 + row) * MROWS + row0 + k0 + ssl8 * 8],
                  &Bs[(w * 16 + q * 8) * 64]);
        }
        __syncthreads();
#pragma nounroll
        for (int s = 0; s < 2; s++) {
            short8 a[4], bb[2];
#pragma unroll
            for (int i = 0; i < 4; i++)
                a[i] = *(const short8*)&Pa[(wm + i * 16 + fr) * 136 + k0 + s * 32 + fq];
#pragma unroll
            for (int j = 0; j < 2; j++)
                bb[j] = *(const short8*)&Bs[(wn + j * 16 + fr) * 64
                                            + (((s * 4 + g) ^ x7) << 3)];
#pragma unroll
            for (int i = 0; i < 4; i++)
#pragma unroll
                for (int j = 0; j < 2; j++)
                    acc[i][j] = __builtin_amdgcn_mfma_f32_16x16x32_bf16(a[i], bb[j], acc[i][j], 0, 0, 0);
        }
    }

    // ---------------- phase 3: acc += (gamma^i Q) @ Sb (BK=64) ------------
    const size_t sbbase = ((size_t)(b * NCH + c) * DV + dv0) * DH;
    const int xr = t >> 2, xc4 = t & 3;     // A staging: row xr, col groups
    const float gx = exp2f((float)xr * LOG2_GAMMA);   // gamma^i
    for (int d0 = 0; d0 < DH; d0 += 64) {
        __syncthreads();
#pragma unroll
        for (int s = 0; s < 2; s++) {
            const int col = s * 32 + xc4 * 8;
            const unsigned short* src = &Qb[(size_t)(row0 + xr) * DH + d0 + col];
            ushort4 q0 = *(const ushort4*)src;
            ushort4 q1 = *(const ushort4*)(src + 4);
            ushort4 h0, h1;
            h0.x = bf16_rne(b2f(q0.x) * gx); h0.y = bf16_rne(b2f(q0.y) * gx);
            h0.z = bf16_rne(b2f(q0.z) * gx); h0.w = bf16_rne(b2f(q0.w) * gx);
            h1.x = bf16_rne(b2f(q1.x) * gx); h1.y = bf16_rne(b2f(q1.y) * gx);
            h1.z = bf16_rne(b2f(q1.z) * gx); h1.w = bf16_rne(b2f(q1.w) * gx);
            const int wsl = (s * 4 + xc4) ^ (xr & 7);
            *(ushort4*)&As[xr * 64 + wsl * 8] = h0;
            *(ushort4*)&As[xr * 64 + wsl * 8 + 4] = h1;
        }
#pragma unroll
        for (int q = 0; q < 2; q++) {
            const int row = w * 16 + q * 8 + rl8;
            gld16(&Sb[sbbase + (size_t)row * DH + d0 + ssl8 * 8],
                  &Bs[(w * 16 + q * 8) * 64]);
        }
        __syncthreads();
#pragma nounroll
        for (int s = 0; s < 2; s++) {
            short8 a[4], bb[2];
#pragma unroll
            for (int i = 0; i < 4; i++)
                a[i] = *(const short8*)&As[(wm + i * 16 + fr) * 64
                                           + (((s * 4 + g) ^ x7) << 3)];
#pragma unroll
            for (int j = 0; j < 2; j++)
                bb[j] = *(const short8*)&Bs[(wn + j * 16 + fr) * 64
                                            + (((s * 4 + g) ^ x7) << 3)];
#pragma unroll
            for (int i = 0; i < 4; i++)
#pragma unroll
                for (int j = 0; j < 2; j++)
                    acc[i][j] = __builtin_amdgcn_mfma_f32_16x16x32_bf16(a[i], bb[j], acc[i][j], 0, 0, 0);
        }
    }

    // epilogue: fp32 store
#pragma unroll
    for (int i = 0; i < 4; i++)
#pragma unroll
        for (int j = 0; j < 2; j++) {
            const int dv = dv0 + wn + j * 16 + cl;
#pragma unroll
            for (int r = 0; r < 4; r++) {
                const int m = row0 + wm + i * 16 + rq + r;
                out[(size_t)m * DV + dv] = acc[i][j][r];
            }
        }
}

// ---------------------------------------------------------------------------
extern "C" void kernel_launch(void* const* d_in, const int* in_sizes, int n_in,
                              void* d_out, int out_size, void* d_ws, size_t ws_size,
                              hipStream_t stream) {
    const float* X  = (const float*)d_in[0];
    const float* WQ = (const float*)d_in[1];
    const float* WK = (const float*)d_in[2];
    const float* WV = (const float*)d_in[3];
    float* out = (float*)d_out;

    // Workspace layout (bf16 unless noted):
    //   Qb 8.4 | Kb 8.4 | Kt 8.4 | Vt 16.8 | Sb 33.5 | Ut fp32 67.1 | Bt 4.2
    //   Xb (67.1) OVERLAPS Ut (Xb dead after qkv; Ut written after). ~147 MB.
    char* ws = (char*)d_ws;
    unsigned short* Qb = (unsigned short*)ws;
    unsigned short* Kb = Qb + (size_t)MROWS * DH;
    unsigned short* Kt = Kb + (size_t)MROWS * DH;
    unsigned short* Vt = Kt + (size_t)MROWS * DH;
    unsigned short* Sb = Vt + (size_t)MROWS * DV;
    float*          Ut = (float*)(Sb + (size_t)NB * NCH * DV * DH);
    unsigned short* Xb = (unsigned short*)Ut;       // overlap
    unsigned short* Bt = (unsigned short*)(Ut + (size_t)NB * NCH * DV * DH);

    xcvt_kernel<<<(MROWS * HID / 4) / 256, 256, 0, stream>>>(X, Xb);
    wcvt_kernel<<<512, 256, 0, stream>>>(WQ, WK, WV, Bt);
    qkv_mfma_kernel<<<256, 512, 0, stream>>>(Xb, Bt, Qb, Kb, Kt, Vt);
    chunk_kv_kernel<<<1024, 512, 0, stream>>>(Kt, Vt, Ut);
    scan_kernel<<<2048, 256, 0, stream>>>(Ut, Sb);
    out_mfma_kernel<<<512, 512, 0, stream>>>(Qb, Kb, Vt, Sb, out);
}

// Round 8
// 356.644 us; speedup vs baseline: 1.0309x; 1.0194x over previous
//
#include <hip/hip_runtime.h>
#include <math.h>

#define NB 4
#define SEQ 4096
#define HID 2048
#define DH 256
#define DV 512
#define CHUNK 128
#define NCH 32                  // SEQ/CHUNK
#define MROWS (NB * SEQ)        // 16384
#define GAMMA 0.96875f
#define GAMMA_INV 1.0322580645161290f
// log2(0.96875)
#define LOG2_GAMMA (-0.045803689613124794f)
// log2(10000)
#define LOG2_10000 13.287712379549449f

typedef __attribute__((ext_vector_type(8))) short short8;
typedef __attribute__((ext_vector_type(4))) float floatx4;

// ---------------------------------------------------------------------------
// helpers
// ---------------------------------------------------------------------------
__device__ __forceinline__ unsigned short bf16_rne(float v) {
    unsigned int u = __float_as_uint(v);
    u += 0x7fff + ((u >> 16) & 1);
    return (unsigned short)(u >> 16);
}
__device__ __forceinline__ float b2f(unsigned short h) {
    return __uint_as_float((unsigned int)h << 16);
}

// async global->LDS, 16 bytes per lane. LDS dest = wave-uniform base + lane*16.
__device__ __forceinline__ void gld16(const void* g, void* l) {
    __builtin_amdgcn_global_load_lds(
        reinterpret_cast<const __attribute__((address_space(1))) unsigned int*>(
            reinterpret_cast<uintptr_t>(g)),
        reinterpret_cast<__attribute__((address_space(3))) unsigned int*>(
            reinterpret_cast<uintptr_t>(l)),
        16, 0, 0);
}

// ---------------------------------------------------------------------------
// Kernel 0a: X fp32 -> bf16 row-major [M][K].
// ---------------------------------------------------------------------------
__global__ __launch_bounds__(256) void xcvt_kernel(
    const float* __restrict__ X, unsigned short* __restrict__ Xb)
{
    const int i = blockIdx.x * 256 + threadIdx.x;   // one float4 per thread
    float4 x = ((const float4*)X)[i];
    ushort4 h;
    h.x = bf16_rne(x.x); h.y = bf16_rne(x.y);
    h.z = bf16_rne(x.z); h.w = bf16_rne(x.w);
    ((ushort4*)Xb)[i] = h;
}

// ---------------------------------------------------------------------------
// Kernel 0b: W_Q|W_K|W_V fp32 [K][Nregion] -> transposed packed bf16 Bt[n][k].
// ---------------------------------------------------------------------------
__global__ __launch_bounds__(256) void wcvt_kernel(
    const float* __restrict__ WQ, const float* __restrict__ WK,
    const float* __restrict__ WV, unsigned short* __restrict__ Bt)
{
    __shared__ unsigned short sh[64][65];
    const int bid = blockIdx.x;         // 32 k-tiles * 16 n-tiles
    const int kt = bid & 31;
    const int ntile = bid >> 5;
    const int k0 = kt * 64, n0 = ntile * 64;

    const float* W; int ld, nl0;
    if (n0 < 256)      { W = WQ; ld = DH; nl0 = n0; }
    else if (n0 < 512) { W = WK; ld = DH; nl0 = n0 - 256; }
    else               { W = WV; ld = DV; nl0 = n0 - 512; }

    const int t = threadIdx.x;
#pragma unroll
    for (int p = 0; p < 4; p++) {
        const int kl = (t >> 4) + p * 16;
        const int ng = (t & 15) * 4;
        float4 w = *(const float4*)&W[(size_t)(k0 + kl) * ld + nl0 + ng];
        sh[kl][ng + 0] = bf16_rne(w.x);
        sh[kl][ng + 1] = bf16_rne(w.y);
        sh[kl][ng + 2] = bf16_rne(w.z);
        sh[kl][ng + 3] = bf16_rne(w.w);
    }
    __syncthreads();
#pragma unroll
    for (int p = 0; p < 4; p++) {
        const int nl = (t >> 4) + p * 16;
        const int kg = (t & 15) * 4;
        ushort4 h;
        h.x = sh[kg + 0][nl]; h.y = sh[kg + 1][nl];
        h.z = sh[kg + 2][nl]; h.w = sh[kg + 3][nl];
        *(ushort4*)&Bt[(size_t)(n0 + nl) * HID + k0 + kg] = h;
    }
}

// ---------------------------------------------------------------------------
// Kernel 1: QKV projection, bf16 MFMA + xPos epilogue.
// M=16384, N=1024, K=2048. 256x256 tile, 8 waves (2Mx4N), BK=64.
// ROUND 7: m201-faithful 8-phase counted-vmcnt schedule. 2 K-tiles/iter,
// per phase {ds_read subtile | stage 1 half-tile | barrier | MFMA | barrier}.
// Half-tile slot table (iter computes t0=kt buf0, t1=kt+1 buf1):
//   P1/P2: A-h0/h1(kt+1)->buf1   (free since prev-P7; used P5/P7)
//   P3/P4: B-h0/h1(kt+2)->buf0   (free after P2; used next-P1/P2)
//   P5/P6: A-h0/h1(kt+2)->buf0   (free after P3; used next-P1/P3)
//   P7/P8: B-h0/h1(kt+3)->buf1   (free after P6; used next-P5/P6)
// vmcnt(4) before P4/P8 barriers ONLY (youngest 2 half-tiles may fly);
// never drains to 0 mid-loop (kt=30 P4 uses 0: P1/P2 are youngest there).
// Race-free: each region staged only after the closing barrier of its
// last-read phase; reads proven landed by vmcnt+barrier ordering.
// XOR slot-swizzle (round 2, measured 0 conflicts) kept.
// ---------------------------------------------------------------------------
__global__ __launch_bounds__(512, 2) void qkv_mfma_kernel(
    const unsigned short* __restrict__ Xb, const unsigned short* __restrict__ Bt,
    unsigned short* __restrict__ Qb, unsigned short* __restrict__ Kb,
    unsigned short* __restrict__ Kt, unsigned short* __restrict__ Vt)
{
    __shared__ unsigned short lds[2 * 32768];   // [buf][A 256x64 | B 256x64]

    // XCD-aware map: same-XCD blocks share the same A-panel (mt), 4 n-tiles.
    const int bid = blockIdx.x;          // 256 blocks
    const int xcd = bid & 7;
    const int idx = bid >> 3;            // 0..31
    const int mt  = (xcd << 3) | (idx >> 2);   // 64 m-tiles
    const int nt  = idx & 3;             // 4 n-tiles
    const int m0 = mt * 256, n0 = nt * 256;

    const int t = threadIdx.x;
    const int w = t >> 6, lane = t & 63;   // 8 waves
    const int wr = w >> 2;               // 0..1: row half (128 rows)
    const int wc = w & 3;                // 0..3: col quarter (64 cols)

    floatx4 acc[8][4];
#pragma unroll
    for (int i = 0; i < 8; i++)
#pragma unroll
        for (int j = 0; j < 4; j++) acc[i][j] = (floatx4)0.0f;

    // staging addressing: per gld16, lane l -> row rl = l>>3, LDS slot l&7
    // holding global slot (l&7)^rl  (XOR swizzle, row&7 == rl).
    const int rl = lane >> 3;
    const int sg = (lane & 7) ^ rl;

    // fragment addressing: row r, slot_g = (s<<2)|g; LDS slot = slot_g ^ (r&7)
    const int fr = lane & 15, g = lane >> 4;
    const int x7 = fr & 7;
    const int soff0 = ((g ^ x7) << 3);          // s=0, in ushort units
    const int soff1 = (((4 | g) ^ x7) << 3);    // s=1

#define STAGE_HT(isB, h, dbuf, ktile)                                         \
    {                                                                         \
        const unsigned short* gsrc =                                          \
            ((isB) ? Bt + (size_t)(n0 + (h) * 128 + w * 16 + rl) * HID        \
                   : Xb + (size_t)(m0 + (h) * 128 + w * 16 + rl) * HID)       \
            + (size_t)(ktile) * 64 + sg * 8;                                  \
        unsigned short* ldst = &lds[(dbuf) * 32768 + ((isB) ? 16384 : 0)      \
                                    + ((h) * 128 + w * 16) * 64];             \
        gld16(gsrc, ldst);                                                    \
        gld16(gsrc + (size_t)8 * HID, ldst + 8 * 64);                         \
    }

#define READ_A(ih)                                                            \
    _Pragma("unroll")                                                         \
    for (int i2 = 0; i2 < 4; i2++) {                                          \
        const int row = wr * 128 + ((ih) * 4 + i2) * 16 + fr;                 \
        ah[i2][0] = *(const short8*)&lds[cb + row * 64 + soff0];              \
        ah[i2][1] = *(const short8*)&lds[cb + row * 64 + soff1];              \
    }

#define READ_B(jh)                                                            \
    _Pragma("unroll")                                                         \
    for (int j2 = 0; j2 < 2; j2++) {                                          \
        const int row = wc * 64 + ((jh) * 2 + j2) * 16 + fr;                  \
        bh[(jh) * 2 + j2][0] = *(const short8*)&lds[cb + 16384 + row * 64 + soff0]; \
        bh[(jh) * 2 + j2][1] = *(const short8*)&lds[cb + 16384 + row * 64 + soff1]; \
    }

#define MFMA16(ib, jb)                                                        \
    _Pragma("unroll")                                                         \
    for (int i2 = 0; i2 < 4; i2++)                                            \
        _Pragma("unroll")                                                     \
        for (int j2 = 0; j2 < 2; j2++) {                                      \
            acc[(ib) + i2][(jb) + j2] = __builtin_amdgcn_mfma_f32_16x16x32_bf16( \
                ah[i2][0], bh[(jb) + j2][0], acc[(ib) + i2][(jb) + j2], 0, 0, 0); \
            acc[(ib) + i2][(jb) + j2] = __builtin_amdgcn_mfma_f32_16x16x32_bf16( \
                ah[i2][1], bh[(jb) + j2][1], acc[(ib) + i2][(jb) + j2], 0, 0, 0); \
        }

#define BAR_SB()  { __builtin_amdgcn_s_barrier(); __builtin_amdgcn_sched_barrier(0); }

    // prologue: tile0 A+B (oldest 8 loads), tile1 B (youngest 4).
    STAGE_HT(0, 0, 0, 0); STAGE_HT(0, 1, 0, 0);
    STAGE_HT(1, 0, 0, 0); STAGE_HT(1, 1, 0, 0);
    STAGE_HT(1, 0, 1, 1); STAGE_HT(1, 1, 1, 1);
    asm volatile("s_waitcnt vmcnt(4)" ::: "memory");   // tile0 landed
    BAR_SB();

    for (int kt = 0; kt < 32; kt += 2) {
        short8 ah[4][2], bh[4][2];
        // ================= tile t0 = kt, buf0 =================
        {
            const int cb = 0;
            // ---- P1: Q(0,0) ----
            READ_A(0); READ_B(0);
            STAGE_HT(0, 0, 1, kt + 1);            // A-h0(kt+1) -> buf1
            BAR_SB();
            __builtin_amdgcn_s_setprio(1); MFMA16(0, 0); __builtin_amdgcn_s_setprio(0);
            BAR_SB();
            // ---- P2: Q(0,2) ----
            READ_B(1);
            STAGE_HT(0, 1, 1, kt + 1);            // A-h1(kt+1) -> buf1
            BAR_SB();
            __builtin_amdgcn_s_setprio(1); MFMA16(0, 2); __builtin_amdgcn_s_setprio(0);
            BAR_SB();
            // ---- P3: Q(4,0) ----
            READ_A(1);
            if (kt + 2 < 32) STAGE_HT(1, 0, 0, kt + 2);   // B-h0(kt+2) -> buf0
            BAR_SB();
            __builtin_amdgcn_s_setprio(1); MFMA16(4, 0); __builtin_amdgcn_s_setprio(0);
            BAR_SB();
            // ---- P4: Q(4,2) + vmcnt checkpoint ----
            if (kt + 2 < 32) {
                STAGE_HT(1, 1, 0, kt + 2);        // B-h1(kt+2) -> buf0
                asm volatile("s_waitcnt vmcnt(4)" ::: "memory");  // P1/P2 landed
            } else {
                asm volatile("s_waitcnt vmcnt(0)" ::: "memory");  // last iter: P1/P2 are youngest
            }
            BAR_SB();
            __builtin_amdgcn_s_setprio(1); MFMA16(4, 2); __builtin_amdgcn_s_setprio(0);
            BAR_SB();
        }
        // ================= tile t1 = kt+1, buf1 =================
        {
            const int cb = 32768;
            // ---- P5: Q(0,0) ----
            READ_A(0); READ_B(0);
            if (kt + 2 < 32) STAGE_HT(0, 0, 0, kt + 2);   // A-h0(kt+2) -> buf0
            BAR_SB();
            __builtin_amdgcn_s_setprio(1); MFMA16(0, 0); __builtin_amdgcn_s_setprio(0);
            BAR_SB();
            // ---- P6: Q(0,2) ----
            READ_B(1);
            if (kt + 2 < 32) STAGE_HT(0, 1, 0, kt + 2);   // A-h1(kt+2) -> buf0
            BAR_SB();
            __builtin_amdgcn_s_setprio(1); MFMA16(0, 2); __builtin_amdgcn_s_setprio(0);
            BAR_SB();
            // ---- P7: Q(4,0) ----
            READ_A(1);
            if (kt + 3 < 32) STAGE_HT(1, 0, 1, kt + 3);   // B-h0(kt+3) -> buf1
            BAR_SB();
            __builtin_amdgcn_s_setprio(1); MFMA16(4, 0); __builtin_amdgcn_s_setprio(0);
            BAR_SB();
            // ---- P8: Q(4,2) + vmcnt checkpoint ----
            if (kt + 3 < 32) STAGE_HT(1, 1, 1, kt + 3);   // B-h1(kt+3) -> buf1
            if (kt + 2 < 32)
                asm volatile("s_waitcnt vmcnt(4)" ::: "memory");  // P5/P6 landed
            BAR_SB();
            __builtin_amdgcn_s_setprio(1); MFMA16(4, 2); __builtin_amdgcn_s_setprio(0);
            BAR_SB();
        }
    }
#undef STAGE_HT
#undef READ_A
#undef READ_B
#undef MFMA16
#undef BAR_SB

    // epilogue. C/D layout: col = lane&15, row = (lane>>4)*4 + reg.
    const int cl = lane & 15, rq = (lane >> 4) << 2;
    if (n0 >= 512) {
#pragma unroll
        for (int i = 0; i < 8; i++)
#pragma unroll
            for (int j = 0; j < 4; j++) {
                const int c = n0 - 512 + wc * 64 + j * 16 + cl;   // dv 0..511
#pragma unroll
                for (int r = 0; r < 4; r++) {
                    const int m = m0 + wr * 128 + i * 16 + rq + r;
                    Vt[(size_t)c * MROWS + m] = bf16_rne(acc[i][j][r]);
                }
            }
    } else {
        const bool isQ = (n0 < 256);
        unsigned short* dst = isQ ? Qb : Kb;
        const float sgn = isQ ? 1.f : -1.f;     // K downscaled
#pragma unroll
        for (int j = 0; j < 4; j++) {
            const int c = wc * 64 + j * 16 + cl;        // 0..255 within Q or K
            const float jj = (float)(c >> 1);
            const float sv = (2.f * jj + 0.4f * 256.f) * (1.f / (1.4f * 256.f));
            const float l2sv = __log2f(sv) * sgn * (1.f / 512.f);
            const float invf = exp2f(jj * (-LOG2_10000 / 128.f));
            const bool odd = (c & 1) != 0;
#pragma unroll
            for (int i = 0; i < 8; i++) {
#pragma unroll
                for (int r = 0; r < 4; r++) {
                    const int m = m0 + wr * 128 + i * 16 + rq + r;
                    const float s = (float)(m & (SEQ - 1));
                    const float x = acc[i][j][r];
                    const float p = __shfl_xor(x, 1, 64);   // partner col c^1
                    const float sc = exp2f(s * l2sv);
                    const float ang = s * invf;
                    const float sn = __sinf(ang), cs = __cosf(ang);
                    const float o = odd ? sc * (x * cs + p * sn)
                                        : sc * (x * cs - p * sn);
                    const unsigned short hv = bf16_rne(o);
                    dst[(size_t)m * DH + c] = hv;
                    if (!isQ) Kt[(size_t)c * MROWS + m] = hv;
                }
            }
        }
    }
}

// ---------------------------------------------------------------------------
// Kernel 2: per-chunk U_c^T = V^T diag(gamma^(C-i)) K, via bf16 MFMA.
// ROUND 5: full K=128 staged ONCE (As/Bs 128x128, 32KB each), 2 barriers
// total, slot-16 XOR swizzle -> conflict-free reads. Grid = 1024.
// ---------------------------------------------------------------------------
__global__ __launch_bounds__(512, 2) void chunk_kv_kernel(
    const unsigned short* __restrict__ Kt, const unsigned short* __restrict__ Vt,
    float* __restrict__ Ut)
{
    __shared__ unsigned short As[128 * 128];   // Vt tile, slot16-swizzled
    __shared__ unsigned short Bs[128 * 128];   // scaled Kt tile, slot16-swizzled

    const int bid = blockIdx.x;      // 1024
    const int dht = bid & 1;
    const int vq  = (bid >> 1) & 3;
    const int c   = (bid >> 3) & 31;
    const int b   = bid >> 8;
    const int dh0 = dht * 128, dv0 = vq * 128;
    const int row0 = b * SEQ + c * CHUNK;

    const int t = threadIdx.x;
    const int w = t >> 6, lane = t & 63;
    const int wm = (w & 1) << 6;         // dv offset
    const int wn = (w >> 1) << 5;        // dh offset
    const int fr = lane & 15, g = lane >> 4;

    floatx4 acc[4][2];
#pragma unroll
    for (int i = 0; i < 4; i++)
#pragma unroll
        for (int j = 0; j < 2; j++) acc[i][j] = (floatx4)0.0f;

    // ---- stage A (Vt): 4 gld16/wave, rows w*16+q*4+(lane>>4), slot lane&15.
    // LDS[row][slot] = global[row][slot ^ (row&15)] via per-lane source addr.
    {
        const int ar = lane >> 4, asl = lane & 15;
#pragma unroll
        for (int q = 0; q < 4; q++) {
            const int row = w * 16 + q * 4 + ar;
            const int ssl = asl ^ (row & 15);
            gld16(&Vt[(size_t)(dv0 + row) * MROWS + row0 + ssl * 8],
                  &As[(w * 16 + q * 4) * 128]);
        }
    }
    // ---- stage B (scaled Kt): per thread row kr = t>>2, 4 col-groups of 8.
    {
        const int kr = t >> 2, kc4 = t & 3;
#pragma unroll
        for (int p = 0; p < 4; p++) {
            const int col = kc4 * 8 + p * 32;
            const unsigned short* src = &Kt[(size_t)(dh0 + kr) * MROWS + row0 + col];
            ushort4 k0v = *(const ushort4*)src;
            ushort4 k1v = *(const ushort4*)(src + 4);
            float gsc = exp2f((float)(CHUNK - col) * LOG2_GAMMA);  // gamma^(C-i)
            ushort4 h0, h1;
            h0.x = bf16_rne(b2f(k0v.x) * gsc); gsc *= GAMMA_INV;
            h0.y = bf16_rne(b2f(k0v.y) * gsc); gsc *= GAMMA_INV;
            h0.z = bf16_rne(b2f(k0v.z) * gsc); gsc *= GAMMA_INV;
            h0.w = bf16_rne(b2f(k0v.w) * gsc); gsc *= GAMMA_INV;
            h1.x = bf16_rne(b2f(k1v.x) * gsc); gsc *= GAMMA_INV;
            h1.y = bf16_rne(b2f(k1v.y) * gsc); gsc *= GAMMA_INV;
            h1.z = bf16_rne(b2f(k1v.z) * gsc); gsc *= GAMMA_INV;
            h1.w = bf16_rne(b2f(k1v.w) * gsc);
            const int wsl = (kc4 + p * 4) ^ (kr & 15);   // cs = col>>3
            *(ushort4*)&Bs[kr * 128 + wsl * 8] = h0;
            *(ushort4*)&Bs[kr * 128 + wsl * 8 + 4] = h1;
        }
    }
    __syncthreads();

#pragma nounroll
    for (int s = 0; s < 4; s++) {
        short8 a[4], bb[2];
#pragma unroll
        for (int i = 0; i < 4; i++)
            a[i] = *(const short8*)&As[(wm + i * 16 + fr) * 128
                                       + (((s * 4 + g) ^ fr) << 3)];
#pragma unroll
        for (int j = 0; j < 2; j++)
            bb[j] = *(const short8*)&Bs[(wn + j * 16 + fr) * 128
                                        + (((s * 4 + g) ^ fr) << 3)];
#pragma unroll
        for (int i = 0; i < 4; i++)
#pragma unroll
            for (int j = 0; j < 2; j++)
                acc[i][j] = __builtin_amdgcn_mfma_f32_16x16x32_bf16(a[i], bb[j], acc[i][j], 0, 0, 0);
    }

    // store: C[m=dv][n=dh] -> Ut[((b*32+c)*512 + dv0+m)*256 + dh0+n]
    const int cl = lane & 15, rq = (lane >> 4) << 2;
    const size_t ubase = ((size_t)(b * NCH + c) * DV + dv0) * DH + dh0;
#pragma unroll
    for (int i = 0; i < 4; i++)
#pragma unroll
        for (int j = 0; j < 2; j++) {
            const int n = wn + j * 16 + cl;
#pragma unroll
            for (int r = 0; r < 4; r++) {
                const int m = wm + i * 16 + rq + r;
                Ut[ubase + (size_t)m * DH + n] = acc[i][j][r];
            }
        }
}

// ---------------------------------------------------------------------------
// Kernel 3: exclusive scan over chunks; emits bf16 state Sb[c] = S_c
// (state BEFORE chunk c), layout [b][c][dv][dh] (B-operand-ready).
// ---------------------------------------------------------------------------
__global__ __launch_bounds__(256) void scan_kernel(
    const float* __restrict__ Ut, unsigned short* __restrict__ Sb)
{
    const int t = blockIdx.x * 256 + threadIdx.x;   // 0..524287
    const int b = t >> 17;                          // DV*DH = 131072
    const int r = t & 131071;
    const float gC = exp2f((float)CHUNK * LOG2_GAMMA);
    float s = 0.f;
    const size_t base = (size_t)b * NCH * 131072 + r;
    for (int c = 0; c < NCH; c++) {
        const size_t off = base + (size_t)c * 131072;
        const float u = Ut[off];
        Sb[off] = bf16_rne(s);
        s = gC * s + u;
    }
}

// ---------------------------------------------------------------------------
// Kernel 4: O = (tril(QK^T) .* gamma^(i-j)) @ V  +  (gamma^i Q) @ S_c^T.
// ROUND 5: As/Bs single [128][64] slot-8 XOR-swizzled layout, all phases
// conflict-free. 512 threads = 8 waves, wave 64x32. Grid = 512.
// ---------------------------------------------------------------------------
__global__ __launch_bounds__(512, 1) void out_mfma_kernel(
    const unsigned short* __restrict__ Qb, const unsigned short* __restrict__ Kb,
    const unsigned short* __restrict__ Vt, const unsigned short* __restrict__ Sb,
    float* __restrict__ out)
{
    __shared__ unsigned short Pa[128 * 136];   // P bf16, row stride 136 (pad)
    __shared__ unsigned short As[128 * 64];    // slot8-swizzled
    __shared__ unsigned short Bs[128 * 64];    // slot8-swizzled

    const int bid = blockIdx.x;      // 512
    const int vq = bid & 3;
    const int c  = (bid >> 2) & 31;
    const int b  = bid >> 7;
    const int dv0 = vq * 128;
    const int row0 = b * SEQ + c * CHUNK;

    const int t = threadIdx.x;
    const int w = t >> 6, lane = t & 63;
    const int wm = (w & 1) << 6;         // 0,64
    const int wn = (w >> 1) << 5;        // 0,32,64,96
    const int fr = lane & 15, g = lane >> 4, fq = g * 8;
    const int cl = lane & 15, rq = (lane >> 4) << 2;
    // gld16 staging: 8 rows x 128B per load; LDS slot l&7 holds global
    // slot (l&7)^(row&7), row = base + q*8 + (l>>3).
    const int rl8 = lane >> 3, sl8 = lane & 7;
    const int ssl8 = sl8 ^ rl8;
    const int x7 = fr & 7;

    floatx4 acc[4][2];
#pragma unroll
    for (int i = 0; i < 4; i++)
#pragma unroll
        for (int j = 0; j < 2; j++) acc[i][j] = (floatx4)0.0f;

    // ---------------- phase 1: P = Q K^T (BK=64) ----------------
    for (int d0 = 0; d0 < DH; d0 += 64) {
        __syncthreads();
#pragma unroll
        for (int q = 0; q < 2; q++) {
            const int row = w * 16 + q * 8 + rl8;
            gld16(&Qb[(size_t)(row0 + row) * DH + d0 + ssl8 * 8],
                  &As[(w * 16 + q * 8) * 64]);
            gld16(&Kb[(size_t)(row0 + row) * DH + d0 + ssl8 * 8],
                  &Bs[(w * 16 + q * 8) * 64]);
        }
        __syncthreads();
#pragma nounroll
        for (int s = 0; s < 2; s++) {
            short8 a[4], bb[2];
#pragma unroll
            for (int i = 0; i < 4; i++)
                a[i] = *(const short8*)&As[(wm + i * 16 + fr) * 64
                                           + (((s * 4 + g) ^ x7) << 3)];
#pragma unroll
            for (int j = 0; j < 2; j++)
                bb[j] = *(const short8*)&Bs[(wn + j * 16 + fr) * 64
                                            + (((s * 4 + g) ^ x7) << 3)];
#pragma unroll
            for (int i = 0; i < 4; i++)
#pragma unroll
                for (int j = 0; j < 2; j++)
                    acc[i][j] = __builtin_amdgcn_mfma_f32_16x16x32_bf16(a[i], bb[j], acc[i][j], 0, 0, 0);
        }
    }

    // decay mask + bf16 -> Pa[i][j] (i = q row in chunk, j = k row)
#pragma unroll
    for (int i = 0; i < 4; i++)
#pragma unroll
        for (int j = 0; j < 2; j++) {
            const int jj = wn + j * 16 + cl;
#pragma unroll
            for (int r = 0; r < 4; r++) {
                const int ii = wm + i * 16 + rq + r;
                const int diff = ii - jj;
                const float v = (diff >= 0) ? acc[i][j][r] * exp2f((float)diff * LOG2_GAMMA) : 0.f;
                Pa[ii * 136 + jj] = bf16_rne(v);
            }
            acc[i][j] = (floatx4)0.0f;     // reset for O accumulation
        }

    // ---------------- phase 2: acc = P @ V (BK=64, K=128 total) ----------
    for (int k0 = 0; k0 < CHUNK; k0 += 64) {
        __syncthreads();   // first iter: Pa visible; later: Bs reads done
#pragma unroll
        for (int q = 0; q < 2; q++) {
            const int row = w * 16 + q * 8 + rl8;
            gld16(&Vt[(size_t)(dv0 + row) * MROWS + row0 + k0 + ssl8 * 8],
                  &Bs[(w * 16 + q * 8) * 64]);
        }
        __syncthreads();
#pragma nounroll
        for (int s = 0; s < 2; s++) {
            short8 a[4], bb[2];
#pragma unroll
            for (int i = 0; i < 4; i++)
                a[i] = *(const short8*)&Pa[(wm + i * 16 + fr) * 136 + k0 + s * 32 + fq];
#pragma unroll
            for (int j = 0; j < 2; j++)
                bb[j] = *(const short8*)&Bs[(wn + j * 16 + fr) * 64
                                            + (((s * 4 + g) ^ x7) << 3)];
#pragma unroll
            for (int i = 0; i < 4; i++)
#pragma unroll
                for (int j = 0; j < 2; j++)
                    acc[i][j] = __builtin_amdgcn_mfma_f32_16x16x32_bf16(a[i], bb[j], acc[i][j], 0, 0, 0);
        }
    }

    // ---------------- phase 3: acc += (gamma^i Q) @ Sb (BK=64) ------------
    const size_t sbbase = ((size_t)(b * NCH + c) * DV + dv0) * DH;
    const int xr = t >> 2, xc4 = t & 3;     // A staging: row xr, col groups
    const float gx = exp2f((float)xr * LOG2_GAMMA);   // gamma^i
    for (int d0 = 0; d0 < DH; d0 += 64) {
        __syncthreads();
#pragma unroll
        for (int s = 0; s < 2; s++) {
            const int col = s * 32 + xc4 * 8;
            const unsigned short* src = &Qb[(size_t)(row0 + xr) * DH + d0 + col];
            ushort4 q0 = *(const ushort4*)src;
            ushort4 q1 = *(const ushort4*)(src + 4);
            ushort4 h0, h1;
            h0.x = bf16_rne(b2f(q0.x) * gx); h0.y = bf16_rne(b2f(q0.y) * gx);
            h0.z = bf16_rne(b2f(q0.z) * gx); h0.w = bf16_rne(b2f(q0.w) * gx);
            h1.x = bf16_rne(b2f(q1.x) * gx); h1.y = bf16_rne(b2f(q1.y) * gx);
            h1.z = bf16_rne(b2f(q1.z) * gx); h1.w = bf16_rne(b2f(q1.w) * gx);
            const int wsl = (s * 4 + xc4) ^ (xr & 7);
            *(ushort4*)&As[xr * 64 + wsl * 8] = h0;
            *(ushort4*)&As[xr * 64 + wsl * 8 + 4] = h1;
        }
#pragma unroll
        for (int q = 0; q < 2; q++) {
            const int row = w * 16 + q * 8 + rl8;
            gld16(&Sb[sbbase + (size_t)row * DH + d0 + ssl8 * 8],
                  &Bs[(w * 16 + q * 8) * 64]);
        }
        __syncthreads();
#pragma nounroll
        for (int s = 0; s < 2; s++) {
            short8 a[4], bb[2];
#pragma unroll
            for (int i = 0; i < 4; i++)
                a[i] = *(const short8*)&As[(wm + i * 16 + fr) * 64
                                           + (((s * 4 + g) ^ x7) << 3)];
#pragma unroll
            for (int j = 0; j < 2; j++)
                bb[j] = *(const short8*)&Bs[(wn + j * 16 + fr) * 64
                                            + (((s * 4 + g) ^ x7) << 3)];
#pragma unroll
            for (int i = 0; i < 4; i++)
#pragma unroll
                for (int j = 0; j < 2; j++)
                    acc[i][j] = __builtin_amdgcn_mfma_f32_16x16x32_bf16(a[i], bb[j], acc[i][j], 0, 0, 0);
        }
    }

    // epilogue: fp32 store
#pragma unroll
    for (int i = 0; i < 4; i++)
#pragma unroll
        for (int j = 0; j < 2; j++) {
            const int dv = dv0 + wn + j * 16 + cl;
#pragma unroll
            for (int r = 0; r < 4; r++) {
                const int m = row0 + wm + i * 16 + rq + r;
                out[(size_t)m * DV + dv] = acc[i][j][r];
            }
        }
}

// ---------------------------------------------------------------------------
extern "C" void kernel_launch(void* const* d_in, const int* in_sizes, int n_in,
                              void* d_out, int out_size, void* d_ws, size_t ws_size,
                              hipStream_t stream) {
    const float* X  = (const float*)d_in[0];
    const float* WQ = (const float*)d_in[1];
    const float* WK = (const float*)d_in[2];
    const float* WV = (const float*)d_in[3];
    float* out = (float*)d_out;

    // Workspace layout (bf16 unless noted):
    //   Qb 8.4 | Kb 8.4 | Kt 8.4 | Vt 16.8 | Sb 33.5 | Ut fp32 67.1 | Bt 4.2
    //   Xb (67.1) OVERLAPS Ut (Xb dead after qkv; Ut written after). ~147 MB.
    char* ws = (char*)d_ws;
    unsigned short* Qb = (unsigned short*)ws;
    unsigned short* Kb = Qb + (size_t)MROWS * DH;
    unsigned short* Kt = Kb + (size_t)MROWS * DH;
    unsigned short* Vt = Kt + (size_t)MROWS * DH;
    unsigned short* Sb = Vt + (size_t)MROWS * DV;
    float*          Ut = (float*)(Sb + (size_t)NB * NCH * DV * DH);
    unsigned short* Xb = (unsigned short*)Ut;       // overlap
    unsigned short* Bt = (unsigned short*)(Ut + (size_t)NB * NCH * DV * DH);

    xcvt_kernel<<<(MROWS * HID / 4) / 256, 256, 0, stream>>>(X, Xb);
    wcvt_kernel<<<512, 256, 0, stream>>>(WQ, WK, WV, Bt);
    qkv_mfma_kernel<<<256, 512, 0, stream>>>(Xb, Bt, Qb, Kb, Kt, Vt);
    chunk_kv_kernel<<<1024, 512, 0, stream>>>(Kt, Vt, Ut);
    scan_kernel<<<2048, 256, 0, stream>>>(Ut, Sb);
    out_mfma_kernel<<<512, 512, 0, stream>>>(Qb, Kb, Vt, Sb, out);
}